// Round 5
// baseline (423.917 us; speedup 1.0000x reference)
//
#include <hip/hip_runtime.h>
#include <hip/hip_bf16.h>

typedef __attribute__((ext_vector_type(8))) short bf16x8;
typedef __attribute__((ext_vector_type(4))) float f32x4;
typedef __attribute__((ext_vector_type(4))) unsigned short us4;

__device__ __forceinline__ unsigned short f2bf(float f) {
    unsigned int u = __builtin_bit_cast(unsigned int, f);
    unsigned int r = (u + 0x7FFFu + ((u >> 16) & 1u)) >> 16;
    return (unsigned short)r;
}
__device__ __forceinline__ float bf2f(unsigned short h) {
    unsigned int u = ((unsigned int)h) << 16;
    return __builtin_bit_cast(float, u);
}

__device__ __forceinline__ void gload_lds16(const void* g, void* l) {
    __builtin_amdgcn_global_load_lds(
        (const __attribute__((address_space(1))) unsigned int*)g,
        (__attribute__((address_space(3))) unsigned int*)l, 16, 0, 0);
}

__device__ __forceinline__ bf16x8 pack8(float4 x, float4 y) {
    bf16x8 f;
    f[0] = (short)f2bf(x.x); f[1] = (short)f2bf(x.y);
    f[2] = (short)f2bf(x.z); f[3] = (short)f2bf(x.w);
    f[4] = (short)f2bf(y.x); f[5] = (short)f2bf(y.y);
    f[6] = (short)f2bf(y.z); f[7] = (short)f2bf(y.w);
    return f;
}

// ---------------------------------------------------------------------------
// KV projection, barrier-free register GEMM.
// KV[row][0..255] = relu(social@Wk^T+bk), [256..511] = relu(social@Wv^T+bv).
// 512 blocks x 512 threads (8 waves). NO LDS, NO barriers.
// Wave w owns cols [w*64, w*64+64): W fragments in 128 VGPRs (loaded once,
// L2-hot across blocks). Per 32-row tile: A fragments loaded directly from
// global (coalesced fragment-shaped float4 reads), cvt to bf16, 64 MFMA
// (swapped operands -> lane holds 4 consecutive cols), 8B us4 stores.
// Waves free-run: no vmcnt(0) drains, loads of tile t+1 overlap stores of t.
// ---------------------------------------------------------------------------
__global__ __launch_bounds__(512, 2) void kv_stream(
    const float* __restrict__ A,
    const float* __restrict__ Wk, const float* __restrict__ bk,
    const float* __restrict__ Wv, const float* __restrict__ bv,
    unsigned short* __restrict__ KV)
{
    const int tid = threadIdx.x;
    const int w = tid >> 6, l = tid & 63;
    const int lg = l >> 4, lr = l & 15;
    const size_t mb = (size_t)blockIdx.x * 256;

    const int cb = w * 64;                       // wave's first output col (0..511)
    const float* Wbase = (w < 4) ? Wk : Wv;
    const float* bbase = (w < 4) ? bk : bv;
    const int cw = (w & 3) * 64;                 // col within K or V half

    // ---- W fragments + bias to registers (once per block) ----
    bf16x8 bfrag[4][8];
    float biasv[4][4];
    #pragma unroll
    for (int ni = 0; ni < 4; ++ni) {
        const float* Wr = Wbase + (size_t)(cw + ni * 16 + lr) * 256;
        #pragma unroll
        for (int ks = 0; ks < 8; ++ks) {
            const float* p = Wr + ks * 32 + lg * 8;
            bfrag[ni][ks] = pack8(*(const float4*)p, *(const float4*)(p + 4));
        }
        float4 bb = *(const float4*)(bbase + cw + ni * 16 + lg * 4);
        biasv[ni][0] = bb.x; biasv[ni][1] = bb.y;
        biasv[ni][2] = bb.z; biasv[ni][3] = bb.w;
    }

    // ---- stream 8 tiles of 32 rows ----
    for (int t = 0; t < 8; ++t) {
        const size_t r0 = mb + (size_t)t * 32;

        bf16x8 af[2][8];
        #pragma unroll
        for (int mi = 0; mi < 2; ++mi) {
            const float* Ar = A + (r0 + mi * 16 + lr) * 256;
            #pragma unroll
            for (int ks = 0; ks < 8; ++ks) {
                const float* p = Ar + ks * 32 + lg * 8;
                af[mi][ks] = pack8(*(const float4*)p, *(const float4*)(p + 4));
            }
        }

        f32x4 acc[4][2] = {};
        #pragma unroll
        for (int ks = 0; ks < 8; ++ks)
            #pragma unroll
            for (int ni = 0; ni < 4; ++ni)
                #pragma unroll
                for (int mi = 0; mi < 2; ++mi)
                    acc[ni][mi] = __builtin_amdgcn_mfma_f32_16x16x32_bf16(
                        bfrag[ni][ks], af[mi][ks], acc[ni][mi], 0, 0, 0);

        #pragma unroll
        for (int ni = 0; ni < 4; ++ni) {
            const int j0 = cb + ni * 16 + lg * 4;
            #pragma unroll
            for (int mi = 0; mi < 2; ++mi) {
                size_t m = r0 + mi * 16 + lr;
                us4 h;
                #pragma unroll
                for (int r = 0; r < 4; ++r)
                    h[r] = f2bf(fmaxf(acc[ni][mi][r] + biasv[ni][r], 0.f));
                *(us4*)(KV + m * 512 + j0) = h;
            }
        }
    }
}

// ---------------------------------------------------------------------------
// Small GEMM (M=4096, N=256, K=256), single K-tile, one barrier.
// ---------------------------------------------------------------------------
template<int RELU>
__global__ __launch_bounds__(256) void gemm_proj(
    const float* __restrict__ A, const float* __restrict__ W,
    const float* __restrict__ bias, float* __restrict__ out, float scale)
{
    __shared__ unsigned short As[64 * 256];
    __shared__ unsigned short Bs[64 * 256];
    char* AsB = (char*)As;
    char* BsB = (char*)Bs;

    const int tid = threadIdx.x;
    const int wave = tid >> 6, lane = tid & 63;
    const int m0 = blockIdx.x * 64;
    const int jbase = blockIdx.y * 64;

    #pragma unroll
    for (int i = 0; i < 4; ++i) {
        int f = tid + i * 256;
        int row = f >> 4, seg = f & 15;
        int byte0 = row * 512 + seg * 32;
        int sw = (row & 7) << 4;
        {
            const float* pa = A + (size_t)(m0 + row) * 256 + seg * 16;
            us4 h0 = { f2bf(pa[0]), f2bf(pa[1]), f2bf(pa[2]), f2bf(pa[3]) };
            us4 h1 = { f2bf(pa[4]), f2bf(pa[5]), f2bf(pa[6]), f2bf(pa[7]) };
            us4 h2 = { f2bf(pa[8]), f2bf(pa[9]), f2bf(pa[10]), f2bf(pa[11]) };
            us4 h3 = { f2bf(pa[12]), f2bf(pa[13]), f2bf(pa[14]), f2bf(pa[15]) };
            *(us4*)(AsB + ((byte0 +  0) ^ sw)) = h0;
            *(us4*)(AsB + ((byte0 +  8) ^ sw)) = h1;
            *(us4*)(AsB + ((byte0 + 16) ^ sw)) = h2;
            *(us4*)(AsB + ((byte0 + 24) ^ sw)) = h3;
        }
        {
            const float* pw = W + (size_t)(jbase + row) * 256 + seg * 16;
            us4 h0 = { f2bf(pw[0]), f2bf(pw[1]), f2bf(pw[2]), f2bf(pw[3]) };
            us4 h1 = { f2bf(pw[4]), f2bf(pw[5]), f2bf(pw[6]), f2bf(pw[7]) };
            us4 h2 = { f2bf(pw[8]), f2bf(pw[9]), f2bf(pw[10]), f2bf(pw[11]) };
            us4 h3 = { f2bf(pw[12]), f2bf(pw[13]), f2bf(pw[14]), f2bf(pw[15]) };
            *(us4*)(BsB + ((byte0 +  0) ^ sw)) = h0;
            *(us4*)(BsB + ((byte0 +  8) ^ sw)) = h1;
            *(us4*)(BsB + ((byte0 + 16) ^ sw)) = h2;
            *(us4*)(BsB + ((byte0 + 24) ^ sw)) = h3;
        }
    }
    __syncthreads();

    f32x4 acc[4] = {};
    #pragma unroll
    for (int ks = 0; ks < 8; ++ks) {
        int arow = wave * 16 + (lane & 15);
        int abyte = arow * 512 + ks * 64 + ((lane >> 4) << 4);
        bf16x8 af = *(const bf16x8*)(AsB + (abyte ^ ((arow & 7) << 4)));
        #pragma unroll
        for (int ni = 0; ni < 4; ++ni) {
            int brow = ni * 16 + (lane & 15);
            int bbyte = brow * 512 + ks * 64 + ((lane >> 4) << 4);
            bf16x8 bfr = *(const bf16x8*)(BsB + (bbyte ^ ((brow & 7) << 4)));
            acc[ni] = __builtin_amdgcn_mfma_f32_16x16x32_bf16(bfr, af, acc[ni], 0, 0, 0);
        }
    }

    int m = m0 + wave * 16 + (lane & 15);
    #pragma unroll
    for (int ni = 0; ni < 4; ++ni) {
        int j0 = jbase + ni * 16 + ((lane >> 4) << 2);
        float4 bb = *(const float4*)(bias + j0);
        float4 o;
        o.x = acc[ni][0] + bb.x; o.y = acc[ni][1] + bb.y;
        o.z = acc[ni][2] + bb.z; o.w = acc[ni][3] + bb.w;
        if (RELU) {
            o.x = fmaxf(o.x, 0.f); o.y = fmaxf(o.y, 0.f);
            o.z = fmaxf(o.z, 0.f); o.w = fmaxf(o.w, 0.f);
        }
        o.x *= scale; o.y *= scale; o.z *= scale; o.w *= scale;
        *(float4*)(out + (size_t)m * 256 + j0) = o;
    }
}

// ---------------------------------------------------------------------------
// Attention: 256 threads / sample, wave = head. Stage only the K-halves of
// the len needed rows (<=32KB) via global_load_lds, 2 rows per instruction,
// pre-swizzled source. V read directly from global in PV (128B coalesced per
// half-wave, L2/L3-hot). LDS 34KB -> 4 blocks/CU.
// ---------------------------------------------------------------------------
__global__ __launch_bounds__(256) void attn_kernel(
    const float* __restrict__ Q, const unsigned short* __restrict__ KV,
    const int* __restrict__ starts, const int* __restrict__ ends,
    float* __restrict__ out)
{
    __shared__ unsigned short kls[64 * 256];   // 32KB: row r K-half at bytes [r*512, r*512+512)
    __shared__ float qs[256];
    __shared__ float aw[4][64];

    const int bid = blockIdx.x;
    const int b = ((bid & 7) << 9) | (bid >> 3);   // XCD-chunked (4096 = 8*512)
    const int t = threadIdx.x;
    const int h = t >> 6, ln = t & 63;
    const int start = starts[b];
    const int len = ends[b] - start;   // 1..64

    // stage K-halves: instruction i covers rows 2i, 2i+1 (1KB dest)
    const int nins = (len + 1) >> 1;
    for (int i = h; i < nins; i += 4) {
        int row = 2 * i + (ln >> 5);
        const char* src = (const char*)(KV + (size_t)(start + row) * 512)
                        + (((ln & 31) * 16) ^ ((row & 7) << 4));
        gload_lds16(src, (char*)kls + i * 1024 + ln * 16);
    }
    qs[t] = Q[(size_t)b * 256 + t];
    __syncthreads();

    // q for this head -> registers
    float2 qreg[32];
    #pragma unroll
    for (int j = 0; j < 32; ++j)
        qreg[j] = *(const float2*)(qs + h * 64 + 2 * j);

    // score: lane = neighbor
    float sx = 0.f, sy = 0.f;
    {
        const char* krow = (const char*)kls + ln * 512;
        const int sw = (ln & 7) << 4;
        #pragma unroll
        for (int j8 = 0; j8 < 8; ++j8) {
            bf16x8 kf = *(const bf16x8*)(krow + ((h * 128 + j8 * 16) ^ sw));
            #pragma unroll
            for (int p = 0; p < 4; ++p) {
                float2 q2 = qreg[j8 * 4 + p];
                sx = fmaf(q2.x, bf2f((unsigned short)kf[2 * p]), sx);
                sy = fmaf(q2.y, bf2f((unsigned short)kf[2 * p + 1]), sy);
            }
        }
    }
    float s = (ln < len) ? (sx + sy) : -3.0e38f;
    float mx = s;
    #pragma unroll
    for (int off = 32; off; off >>= 1) mx = fmaxf(mx, __shfl_xor(mx, off));
    float e = (ln < len) ? __expf(s - mx) : 0.f;
    float sum = e;
    #pragma unroll
    for (int off = 32; off; off >>= 1) sum += __shfl_xor(sum, off);
    aw[h][ln] = e / sum;   // wave-local write/read: no block barrier needed

    // PV: half 0 -> m in [0,32), half 1 -> [32,64); lane covers dims 2dl, 2dl+1
    const int half = ln >> 5, dl = ln & 31;
    int nm = len - half * 32; nm = nm < 0 ? 0 : (nm > 32 ? 32 : nm);
    float a0 = 0.f, a1 = 0.f;
    const unsigned short* vb = KV + (size_t)(start + half * 32) * 512 + 256 + h * 64 + 2 * dl;
    for (int mm = 0; mm < nm; ++mm) {
        unsigned int vv = *(const unsigned int*)(vb + (size_t)mm * 512);
        float awm = aw[h][half * 32 + mm];
        a0 = fmaf(awm, __builtin_bit_cast(float, vv << 16), a0);
        a1 = fmaf(awm, __builtin_bit_cast(float, vv & 0xFFFF0000u), a1);
    }
    a0 += __shfl_xor(a0, 32);
    a1 += __shfl_xor(a1, 32);
    if (ln < 32) {
        float2 o; o.x = a0; o.y = a1;
        *(float2*)(out + (size_t)b * 256 + h * 64 + 2 * dl) = o;
    }
}

extern "C" void kernel_launch(void* const* d_in, const int* in_sizes, int n_in,
                              void* d_out, int out_size, void* d_ws, size_t ws_size,
                              hipStream_t stream) {
    const float* enc    = (const float*)d_in[0];
    const float* social = (const float*)d_in[1];
    const float* Wq = (const float*)d_in[2];
    const float* bq = (const float*)d_in[3];
    const float* Wk = (const float*)d_in[4];
    const float* bk = (const float*)d_in[5];
    const float* Wv = (const float*)d_in[6];
    const float* bv = (const float*)d_in[7];
    const float* Wf = (const float*)d_in[8];
    const float* bf = (const float*)d_in[9];
    const int* st = (const int*)d_in[10];
    const int* en = (const int*)d_in[11];
    (void)in_sizes; (void)n_in; (void)out_size; (void)ws_size;

    char* ws = (char*)d_ws;
    unsigned short* KV = (unsigned short*)ws;                       // 128 MB
    float* Qb    = (float*)(ws + 134217728);                        // 4 MB
    float* attnb = (float*)(ws + 134217728 + 4194304);              // 4 MB
    float* outf  = (float*)d_out;

    kv_stream<<<dim3(512), dim3(512), 0, stream>>>(social, Wk, bk, Wv, bv, KV);
    gemm_proj<1><<<dim3(64, 4), dim3(256), 0, stream>>>(enc, Wq, bq, Qb, 0.0625f);
    attn_kernel<<<dim3(4096), dim3(256), 0, stream>>>(Qb, KV, st, en, attnb);
    gemm_proj<0><<<dim3(64, 4), dim3(256), 0, stream>>>(attnb, Wf, bf, outf, 1.0f);
}